// Round 1
// baseline (203.757 us; speedup 1.0000x reference)
//
#include <hip/hip_runtime.h>
#include <math.h>

#define B_ 64
#define F_ 32
#define S_ 512
#define P_ 96
#define E_ 8
#define H_ 2048
#define M_ 2048   // B_*F_ rows, m = b*F_ + f (natural layout of x and output)

// fused expert kernel tiling
#define BM 128
#define BH 128
#define BK 64
#define HGROUPS 4
#define HPG (H_ / HGROUPS)   // 512 H-cols per block
#define NHC (HPG / BH)       // 4 h-chunks
#define NKC (S_ / BK)        // 8 k-chunks

// LDS pitches (elements). 72*2=144B, 136*2=272B -> 16B-aligned rows, +4-bank skew
#define XPITCH 72
#define W1PITCH 72
#define HPITCH 136
#define W2PITCH 136

typedef __bf16 bf16x8 __attribute__((ext_vector_type(8)));
typedef float f32x4 __attribute__((ext_vector_type(4)));
typedef unsigned int u32x4 __attribute__((ext_vector_type(4)));
typedef unsigned int u32x2 __attribute__((ext_vector_type(2)));

#define MFMA16(a, b, c) __builtin_amdgcn_mfma_f32_16x16x32_bf16((a), (b), (c), 0, 0, 0)

__device__ __forceinline__ unsigned short f2bf(float f) {
  unsigned int u = __float_as_uint(f);
  return (unsigned short)((u + 0x7FFFu + ((u >> 16) & 1u)) >> 16);  // RNE
}

// ---------------- x: fp32 [M][S] -> bf16 [M][S] ----------------
__global__ __launch_bounds__(256) void k_convert_x(const float* __restrict__ x,
                                                   unsigned short* __restrict__ xbf) {
  int i = (blockIdx.x * 256 + threadIdx.x) * 4;
  f32x4 v = *(const f32x4*)(x + i);
  unsigned int lo = (unsigned int)f2bf(v[0]) | ((unsigned int)f2bf(v[1]) << 16);
  unsigned int hi = (unsigned int)f2bf(v[2]) | ((unsigned int)f2bf(v[3]) << 16);
  u32x2 o = {lo, hi};
  *(u32x2*)(xbf + i) = o;
}

// ---------------- transpose+cast: fp32 [E][R][C] -> bf16 [E][C][R] ----------------
template <int R, int C>
__global__ __launch_bounds__(256) void k_transpose(const float* __restrict__ in,
                                                   unsigned short* __restrict__ outbf) {
  __shared__ float tile[32][33];
  int e = blockIdx.z;
  const float* src = in + (size_t)e * R * C;
  unsigned short* dst = outbf + (size_t)e * R * C;
  int c0 = blockIdx.x * 32, r0 = blockIdx.y * 32;
  int tx = threadIdx.x & 31, ty = threadIdx.x >> 5;  // ty in [0,8)
#pragma unroll
  for (int i = 0; i < 4; ++i) {
    int r = ty * 4 + i;
    tile[r][tx] = src[(size_t)(r0 + r) * C + c0 + tx];
  }
  __syncthreads();
#pragma unroll
  for (int i = 0; i < 4; ++i) {
    int c = ty * 4 + i;
    dst[(size_t)(c0 + c) * R + r0 + tx] = f2bf(tile[tx][c]);
  }
}

// ---------------- gates: one wave per row m ----------------
__global__ __launch_bounds__(256) void k_gates(const float* __restrict__ te,
                                               const float* __restrict__ Wg,
                                               const float* __restrict__ bg,
                                               float* __restrict__ gates) {
  int wave = threadIdx.x >> 6;
  int lane = threadIdx.x & 63;
  int m = blockIdx.x * 4 + wave;
  const float* trow = te + (size_t)m * S_;
  float acc[E_];
#pragma unroll
  for (int e = 0; e < E_; ++e) acc[e] = 0.f;
  for (int s = lane; s < S_; s += 64) {
    float t = trow[s];
    const f32x4* wgr = (const f32x4*)(Wg + s * E_);
    f32x4 a = wgr[0], b = wgr[1];
    acc[0] += t * a[0]; acc[1] += t * a[1]; acc[2] += t * a[2]; acc[3] += t * a[3];
    acc[4] += t * b[0]; acc[5] += t * b[1]; acc[6] += t * b[2]; acc[7] += t * b[3];
  }
#pragma unroll
  for (int e = 0; e < E_; ++e) {
#pragma unroll
    for (int off = 32; off > 0; off >>= 1) acc[e] += __shfl_xor(acc[e], off, 64);
  }
  if (lane == 0) {
    float lg[E_];
    float m1 = -3.4e38f, m2 = -3.4e38f;
#pragma unroll
    for (int e = 0; e < E_; ++e) {
      float v = acc[e] + bg[e];
      lg[e] = v;
      if (v > m1) { m2 = m1; m1 = v; }
      else if (v > m2) { m2 = v; }
    }
    // softmax(logits)
    float den = 0.f, sm[E_];
#pragma unroll
    for (int e = 0; e < E_; ++e) { sm[e] = expf(lg[e] - m1); den += sm[e]; }
    float inv = 1.f / den;
    // dec = mask ? 10*log(sm+1) : 10*(exp(sm)-1); mask = logits < kth(2nd largest)
    float dmax = -3.4e38f, dec[E_];
#pragma unroll
    for (int e = 0; e < E_; ++e) {
      float p = sm[e] * inv;
      float d = (lg[e] < m2) ? (10.f * logf(p + 1.f)) : (10.f * (expf(p) - 1.f));
      dec[e] = d;
      dmax = fmaxf(dmax, d);
    }
    float dden = 0.f;
#pragma unroll
    for (int e = 0; e < E_; ++e) { dec[e] = expf(dec[e] - dmax); dden += dec[e]; }
    float dinv = 1.f / dden;
#pragma unroll
    for (int e = 0; e < E_; ++e) gates[m * E_ + e] = dec[e] * dinv;
  }
}

// ---------------- losses from gates ----------------
__global__ __launch_bounds__(256) void k_loss(const float* __restrict__ gates,
                                              float* __restrict__ lout) {
  __shared__ float gsum[F_][E_];
  __shared__ float cvs[F_], ents[F_];
  int t = threadIdx.x;          // 256 = F_*E_
  int f = t >> 3, e = t & 7;
  float s = 0.f;
  for (int b = 0; b < B_; ++b) s += gates[(size_t)(b * F_ + f) * E_ + e];
  gsum[f][e] = s;
  __syncthreads();
  if (t < F_) {
    float mean = 0.f;
#pragma unroll
    for (int k = 0; k < E_; ++k) mean += gsum[t][k];
    mean *= (1.f / E_);
    float ss = 0.f;
#pragma unroll
    for (int k = 0; k < E_; ++k) { float d = gsum[t][k] - mean; ss += d * d; }
    float var = (float)P_ * ss / (float)(E_ * P_ - 1);   // ddof=1 over E*P repeated values
    cvs[t] = var / (mean * mean + 1e-10f);
    float ent = 0.f;
#pragma unroll
    for (int k = 0; k < E_; ++k) { float g = gsum[t][k] * (1.f / B_); ent += -g * logf(g + 1e-8f); }
    ents[t] = ent * (1.f / E_);
  }
  __syncthreads();
  if (t == 0) {
    float a = 0.f, b = 0.f;
    for (int k = 0; k < F_; ++k) { a += cvs[k]; b += ents[k]; }
    lout[0] = a;   // selector_loss
    lout[1] = b;   // entropy_loss
  }
}

// ---------------- fused experts: gelu(X@W1)@W2, gated atomic accumulate ----------------
// grid (E_, M_/BM, HGROUPS); expert = blockIdx.x so linear_id%8 == expert -> per-XCD W1 locality
__global__ __launch_bounds__(256, 2) void k_experts(
    const unsigned short* __restrict__ xbf,   // [M][S] bf16
    const unsigned short* __restrict__ w1t,   // [E][H][S] bf16 (transposed: h-major)
    const unsigned short* __restrict__ w2t,   // [E][P][H] bf16 (transposed: p-major)
    const float* __restrict__ b1,             // [E][H]
    const float* __restrict__ b2,             // [E][P]
    const float* __restrict__ gates,          // [M][E]
    float* __restrict__ out)                  // [M][P]
{
  __shared__ __align__(16) unsigned short Xks[BM * XPITCH];   // 128x72  (18.4 KB)
  __shared__ __align__(16) unsigned short Hs[BM * HPITCH];    // 128x136 (34.8 KB)
  __shared__ __align__(16) unsigned short Ws[P_ * W2PITCH];   // union: W1 chunk (128x72) / W2 chunk (96x136) (26.1 KB)

  const int tid = threadIdx.x;
  const int wave = tid >> 6, lane = tid & 63;
  const int l15 = lane & 15, quad = lane >> 4;
  const int e = blockIdx.x;
  const int m0 = blockIdx.y * BM;
  const int hbase = blockIdx.z * HPG;

  const unsigned short* __restrict__ w1e = w1t + ((size_t)e * H_ + hbase) * S_;
  const unsigned short* __restrict__ w2e = w2t + (size_t)e * P_ * H_ + hbase;
  const float* __restrict__ b1e = b1 + e * H_ + hbase;

  const int rw = (wave >> 1) * 64;   // wave's row offset in the 128-row tile
  const int cw = (wave & 1) * 64;    // wave's col offset in the 128-col h-chunk

  // staging decompositions
  const int srow = tid >> 3;          // X/W1: 32 rows per pass
  const int scol = (tid & 7) * 8;     // 8 bf16 per thread
  const int trow = tid >> 4;          // W2: 16 rows per pass
  const int tcol = (tid & 15) * 8;

  const f32x4 fz = {0.f, 0.f, 0.f, 0.f};
  f32x4 acc2[2][6];
#pragma unroll
  for (int rt = 0; rt < 2; ++rt)
#pragma unroll
    for (int j = 0; j < 6; ++j) acc2[rt][j] = fz;

  for (int hc = 0; hc < NHC; ++hc) {
    f32x4 acc1[4][4];
#pragma unroll
    for (int i = 0; i < 4; ++i)
#pragma unroll
      for (int j = 0; j < 4; ++j) acc1[i][j] = fz;

    u32x4 xreg[4], w1reg[4];
#pragma unroll
    for (int p = 0; p < 4; ++p) {     // preload k-chunk 0
      int rr = p * 32 + srow;
      xreg[p]  = *(const u32x4*)(xbf + (size_t)(m0 + rr) * S_ + scol);
      w1reg[p] = *(const u32x4*)(w1e + (size_t)(hc * BH + rr) * S_ + scol);
    }
    for (int kc = 0; kc < NKC; ++kc) {
      __syncthreads();                 // prior LDS consumers done
#pragma unroll
      for (int p = 0; p < 4; ++p) {
        int rr = p * 32 + srow;
        *(u32x4*)&Xks[rr * XPITCH + scol] = xreg[p];
        *(u32x4*)&Ws[rr * W1PITCH + scol] = w1reg[p];
      }
      __syncthreads();                 // stage visible
      if (kc + 1 < NKC) {              // prefetch next chunk (overlaps MFMA below)
#pragma unroll
        for (int p = 0; p < 4; ++p) {
          int rr = p * 32 + srow;
          xreg[p]  = *(const u32x4*)(xbf + (size_t)(m0 + rr) * S_ + (kc + 1) * BK + scol);
          w1reg[p] = *(const u32x4*)(w1e + (size_t)(hc * BH + rr) * S_ + (kc + 1) * BK + scol);
        }
      }
#pragma unroll
      for (int kk = 0; kk < 2; ++kk) {
        bf16x8 af[4], bfr[4];
#pragma unroll
        for (int i = 0; i < 4; ++i)
          af[i] = *(const bf16x8*)&Xks[(rw + i * 16 + l15) * XPITCH + kk * 32 + quad * 8];
#pragma unroll
        for (int j = 0; j < 4; ++j)
          bfr[j] = *(const bf16x8*)&Ws[(cw + j * 16 + l15) * W1PITCH + kk * 32 + quad * 8];
#pragma unroll
        for (int i = 0; i < 4; ++i)
#pragma unroll
          for (int j = 0; j < 4; ++j)
            acc1[i][j] = MFMA16(af[i], bfr[j], acc1[i][j]);
      }
    }
    // prefetch W2 chunk (global latency overlaps gelu below)
    u32x4 w2reg[6];
#pragma unroll
    for (int p = 0; p < 6; ++p) {
      int rr = p * 16 + trow;
      w2reg[p] = *(const u32x4*)(w2e + (size_t)rr * H_ + hc * BH + tcol);
    }
    // bias + exact gelu -> Hs (bf16)
#pragma unroll
    for (int j = 0; j < 4; ++j) {
      int n = hc * BH + cw + j * 16 + l15;
      float bias = b1e[n];
#pragma unroll
      for (int i = 0; i < 4; ++i) {
#pragma unroll
        for (int r = 0; r < 4; ++r) {
          float xv = acc1[i][j][r] + bias;
          float g = 0.5f * xv * (1.0f + erff(xv * 0.70710678118654752f));
          Hs[(rw + i * 16 + quad * 4 + r) * HPITCH + cw + j * 16 + l15] = f2bf(g);
        }
      }
    }
    __syncthreads();   // all W1-chunk reads done (Ws reuse) + Hs writes done
#pragma unroll
    for (int p = 0; p < 6; ++p) {
      int rr = p * 16 + trow;
      *(u32x4*)&Ws[rr * W2PITCH + tcol] = w2reg[p];
    }
    __syncthreads();   // W2 chunk + Hs visible
    // GEMM2: acc2 += Hs[128xBH] @ W2chunk[BHx96]; wave handles rows [wave*32, wave*32+32)
#pragma unroll
    for (int kk = 0; kk < 4; ++kk) {
      bf16x8 a0 = *(const bf16x8*)&Hs[(wave * 32 + l15) * HPITCH + kk * 32 + quad * 8];
      bf16x8 a1 = *(const bf16x8*)&Hs[(wave * 32 + 16 + l15) * HPITCH + kk * 32 + quad * 8];
#pragma unroll
      for (int j = 0; j < 6; ++j) {
        bf16x8 b = *(const bf16x8*)&Ws[(j * 16 + l15) * W2PITCH + kk * 32 + quad * 8];
        acc2[0][j] = MFMA16(a0, b, acc2[0][j]);
        acc2[1][j] = MFMA16(a1, b, acc2[1][j]);
      }
    }
  }
  // epilogue: out[m,p] += gates[m,e] * (acc + b2[e,p] (once, hgroup 0))
#pragma unroll
  for (int rt = 0; rt < 2; ++rt) {
#pragma unroll
    for (int r = 0; r < 4; ++r) {
      int m = m0 + wave * 32 + rt * 16 + quad * 4 + r;
      float g = gates[m * E_ + e];
#pragma unroll
      for (int j = 0; j < 6; ++j) {
        int col = j * 16 + l15;
        float v = acc2[rt][j][r];
        if (blockIdx.z == 0) v += b2[e * P_ + col];
        atomicAdd(&out[(size_t)m * P_ + col], g * v);
      }
    }
  }
}

extern "C" void kernel_launch(void* const* d_in, const int* in_sizes, int n_in,
                              void* d_out, int out_size, void* d_ws, size_t ws_size,
                              hipStream_t stream) {
  const float* x  = (const float*)d_in[0];
  const float* te = (const float*)d_in[1];
  const float* Wg = (const float*)d_in[2];
  const float* bg = (const float*)d_in[3];
  const float* W1 = (const float*)d_in[4];
  const float* b1 = (const float*)d_in[5];
  const float* W2 = (const float*)d_in[6];
  const float* b2 = (const float*)d_in[7];
  float* out = (float*)d_out;

  char* ws = (char*)d_ws;
  float* gates        = (float*)ws;                                   // 65,536 B
  unsigned short* xbf = (unsigned short*)(ws + 65536);                // 2,097,152 B
  unsigned short* w1t = (unsigned short*)(ws + 65536 + 2097152);      // 16,777,216 B
  unsigned short* w2t = (unsigned short*)(ws + 65536 + 2097152 + 16777216);  // 3,145,728 B

  hipMemsetAsync(d_out, 0, (size_t)out_size * sizeof(float), stream);
  k_convert_x<<<(M_ * S_) / 1024, 256, 0, stream>>>(x, xbf);
  k_transpose<S_, H_><<<dim3(H_ / 32, S_ / 32, E_), 256, 0, stream>>>(W1, w1t);
  k_transpose<H_, P_><<<dim3(P_ / 32, H_ / 32, E_), 256, 0, stream>>>(W2, w2t);
  k_gates<<<M_ / 4, 256, 0, stream>>>(te, Wg, bg, gates);
  k_loss<<<1, 256, 0, stream>>>(gates, out + (size_t)M_ * P_);
  k_experts<<<dim3(E_, M_ / BM, HGROUPS), 256, 0, stream>>>(xbf, w1t, w2t, b1, b2, gates, out);
}